// Round 2
// baseline (1622.751 us; speedup 1.0000x reference)
//
#include <hip/hip_runtime.h>

// Problem constants
constexpr int TT = 512;    // sequence length
constexpr int BB = 2048;   // batch
constexpr int HH = 11;     // hidden size
constexpr int GG = 44;     // 4*HH gates
constexpr int NL = 5;      // layers

__device__ __forceinline__ float readlane_f(float v, int l) {
    return __int_as_float(__builtin_amdgcn_readlane(__float_as_int(v), l));
}

// inp[b][t] = sum_k x[b][0][k][t]   (x pre-offset to chunk base; b within chunk)
__global__ void reduce_x(const float* __restrict__ x, float* __restrict__ inp) {
    int t = blockIdx.x * 256 + threadIdx.x;   // grid.x = 2 -> t in [0,512)
    int b = blockIdx.y;
    const float* p = x + (size_t)b * 32 * TT + t;
    float s = 0.f;
#pragma unroll
    for (int k = 0; k < 32; k++) s += p[k * TT];
    inp[(size_t)b * TT + t] = s;
}

// One wave per (batch, dir). Lane layout: lane = 4*u + q, u = hidden unit,
// q = gate class (0:i 1:f 2:g 3:o). Weight row in W is q*HH + u.
// Lanes with u >= 11 run with zero weights (benign), stores masked.
template <int IND>
__global__ __launch_bounds__(256, 4) void lstm_layer(
    const float* __restrict__ xin,   // [chunk][TT][IND]
    float* __restrict__ out,         // [chunk][TT][22], this dir writes cols d*11+u
    const float* __restrict__ Wih,   // [2][GG][IND]  (layer base)
    const float* __restrict__ Whh,   // [2][GG][HH]
    const float* __restrict__ bih,   // [2][GG]
    const float* __restrict__ bhh)   // [2][GG]
{
    int tid  = threadIdx.x;
    int lane = tid & 63;
    int seq  = __builtin_amdgcn_readfirstlane((int)blockIdx.x * 4 + (tid >> 6));
    int b = seq >> 1;   // batch index within chunk
    int d = seq & 1;    // direction
    int u = lane >> 2;
    int q = lane & 3;
    int grow = q * HH + u;
    bool active = (u < HH);

    float wih[IND];
    float whh[HH];
    float bias = 0.f;
    if (active) {
        const float* wi = Wih + (size_t)(d * GG + grow) * IND;
#pragma unroll
        for (int k = 0; k < IND; k++) wih[k] = wi[k];
        const float* wh = Whh + (size_t)(d * GG + grow) * HH;
#pragma unroll
        for (int j = 0; j < HH; j++) whh[j] = wh[j];
        bias = bih[d * GG + grow] + bhh[d * GG + grow];
    } else {
#pragma unroll
        for (int k = 0; k < IND; k++) wih[k] = 0.f;
#pragma unroll
        for (int j = 0; j < HH; j++) whh[j] = 0.f;
    }

    // branchless activation: act = a * sigmoid(m*x) + o  (tanh = 2*sig(2x)-1)
    const float L2E = 1.4426950408889634f;
    float escale = (q == 2) ? (-2.f * L2E) : (-L2E);
    float ascale = (q == 2) ? 2.f : 1.f;
    float aoff   = (q == 2) ? -1.f : 0.f;

    float hs[HH];
#pragma unroll
    for (int j = 0; j < HH; j++) hs[j] = 0.f;
    float c = 0.f;

    const float* xb = xin + (size_t)b * TT * IND;
    float* ob = out + (size_t)b * TT * 22 + d * HH + u;

    for (int s = 0; s < TT; s++) {
        int t = d ? (TT - 1 - s) : s;
        const float* xt = xb + (size_t)t * IND;
        float pre = bias;
#pragma unroll
        for (int k = 0; k < IND; k++) pre = fmaf(xt[k], wih[k], pre);
#pragma unroll
        for (int j = 0; j < HH; j++) pre = fmaf(hs[j], whh[j], pre);

        float e   = __builtin_amdgcn_exp2f(escale * pre);
        float act = fmaf(ascale, __builtin_amdgcn_rcpf(1.f + e), aoff);

        float iv = __shfl(act, 0, 4);
        float fv = __shfl(act, 1, 4);
        float gv = __shfl(act, 2, 4);
        float ov = __shfl(act, 3, 4);

        c = fmaf(fv, c, iv * gv);
        float e2 = __builtin_amdgcn_exp2f(-2.f * L2E * c);
        float th = fmaf(2.f, __builtin_amdgcn_rcpf(1.f + e2), -1.f);
        float h  = ov * th;

        if (q == 0 && active) ob[(size_t)t * 22] = h;

#pragma unroll
        for (int j = 0; j < HH; j++) hs[j] = readlane_f(h, 4 * j);
    }
}

extern "C" void kernel_launch(void* const* d_in, const int* in_sizes, int n_in,
                              void* d_out, int out_size, void* d_ws, size_t ws_size,
                              hipStream_t stream) {
    const float* x        = (const float*)d_in[0]; // [2048,1,32,512]
    const float* W_ih0    = (const float*)d_in[1]; // [2,44,1]
    const float* W_ih_rest= (const float*)d_in[2]; // [4,2,44,22]
    const float* W_hh     = (const float*)d_in[3]; // [5,2,44,11]
    const float* b_ih     = (const float*)d_in[4]; // [5,2,44]
    const float* b_hh     = (const float*)d_in[5]; // [5,2,44]
    float* out = (float*)d_out;                    // [2048,512,22]

    // Workspace budget: one ping buffer of chunk*TT*22 floats (45056 B per
    // batch element). Pick largest power-of-two chunk that fits ws_size;
    // the x-reduction for the chunk is staged in the same buffer (its
    // lifetime ends when layer 1 overwrites it). d_out is the pong buffer.
    const size_t perB = (size_t)TT * 22 * sizeof(float);
    int chunk = BB;
    while (chunk > 2 && (size_t)chunk * perB > ws_size) chunk >>= 1;
    float* wsbuf = (float*)d_ws;   // [chunk][TT][22] (and [chunk][TT] for reduce)

    for (int c0 = 0; c0 < BB; c0 += chunk) {
        const float* xc  = x + (size_t)c0 * 32 * TT;
        float*       outc = out + (size_t)c0 * TT * 22;
        const int nblk = (chunk * 2) / 4;  // 4 sequences (waves) per block

        // stage x-reduction for this chunk in wsbuf (read only by layer 0)
        reduce_x<<<dim3(2, chunk), 256, 0, stream>>>(xc, wsbuf);

        // layer 0: input dim 1, wsbuf -> outc
        lstm_layer<1><<<nblk, 256, 0, stream>>>(wsbuf, outc, W_ih0, W_hh, b_ih, b_hh);

        // layers 1..4 ping-pong: outc -> wsbuf -> outc -> wsbuf -> outc
        for (int l = 1; l < NL; l++) {
            const float* src = (l & 1) ? outc : wsbuf;
            float*       dst = (l & 1) ? wsbuf : outc;
            lstm_layer<22><<<nblk, 256, 0, stream>>>(
                src, dst,
                W_ih_rest + (size_t)(l - 1) * 2 * GG * 22,
                W_hh + (size_t)l * 2 * GG * HH,
                b_ih + (size_t)l * 2 * GG,
                b_hh + (size_t)l * 2 * GG);
        }
    }
}

// Round 3
// 1535.518 us; speedup vs baseline: 1.0568x; 1.0568x over previous
//
#include <hip/hip_runtime.h>

// Problem constants
constexpr int TT = 512;    // sequence length
constexpr int BB = 2048;   // batch
constexpr int HH = 11;     // hidden size
constexpr int GG = 44;     // 4*HH gates
constexpr int NL = 5;      // layers

typedef float v2f __attribute__((ext_vector_type(2)));

__device__ __forceinline__ float readlane_f(float v, int l) {
    return __int_as_float(__builtin_amdgcn_readlane(__float_as_int(v), l));
}
// quad_perm broadcast of lane q within each quad (ctrl = q * 0x55)
__device__ __forceinline__ float dpp_q0(float v) {
    return __int_as_float(__builtin_amdgcn_mov_dpp(__float_as_int(v), 0x00, 0xF, 0xF, false));
}
__device__ __forceinline__ float dpp_q1(float v) {
    return __int_as_float(__builtin_amdgcn_mov_dpp(__float_as_int(v), 0x55, 0xF, 0xF, false));
}
__device__ __forceinline__ float dpp_q2(float v) {
    return __int_as_float(__builtin_amdgcn_mov_dpp(__float_as_int(v), 0xAA, 0xF, 0xF, false));
}
__device__ __forceinline__ float dpp_q3(float v) {
    return __int_as_float(__builtin_amdgcn_mov_dpp(__float_as_int(v), 0xFF, 0xF, 0xF, false));
}

// inp[b][t] = sum_k x[b][0][k][t]   (x pre-offset to chunk base; b within chunk)
__global__ void reduce_x(const float* __restrict__ x, float* __restrict__ inp) {
    int t = blockIdx.x * 256 + threadIdx.x;   // grid.x = 2 -> t in [0,512)
    int b = blockIdx.y;
    const float* p = x + (size_t)b * 32 * TT + t;
    float s = 0.f;
#pragma unroll
    for (int k = 0; k < 32; k++) s += p[k * TT];
    inp[(size_t)b * TT + t] = s;
}

// One wave per (batch, dir). Lane = 4*u + q, u = hidden unit, q = gate
// (0:i 1:f 2:g 3:o). Weight row in W is q*HH + u. Lanes with u >= 11 run
// with zero weights (benign), stores masked.
template <int IND>
__global__ __launch_bounds__(256, 4) void lstm_layer(
    const float* __restrict__ xin,   // [chunk][TT][IND]
    float* __restrict__ out,         // [chunk][TT][22]
    const float* __restrict__ Wih,   // [2][GG][IND]
    const float* __restrict__ Whh,   // [2][GG][HH]
    const float* __restrict__ bih,   // [2][GG]
    const float* __restrict__ bhh)   // [2][GG]
{
    constexpr int NP = IND / 2;      // v2f pairs (11 for IND=22, 0 for IND=1)

    int tid  = threadIdx.x;
    int lane = tid & 63;
    int seq  = __builtin_amdgcn_readfirstlane((int)blockIdx.x * 4 + (tid >> 6));
    int b = seq >> 1;
    int d = seq & 1;
    int u = lane >> 2;
    int q = lane & 3;
    int grow = q * HH + u;
    bool active = (u < HH);

    v2f   wih2[NP > 0 ? NP : 1];
    float wih0 = 0.f;
    float whh[HH];
    float bias = 0.f;
    if (active) {
        const float* wi = Wih + (size_t)(d * GG + grow) * IND;
        if constexpr (IND == 1) {
            wih0 = wi[0];
        } else {
#pragma unroll
            for (int p = 0; p < NP; p++) wih2[p] = ((const v2f*)wi)[p];
        }
        const float* wh = Whh + (size_t)(d * GG + grow) * HH;
#pragma unroll
        for (int j = 0; j < HH; j++) whh[j] = wh[j];
        bias = bih[d * GG + grow] + bhh[d * GG + grow];
    } else {
        if constexpr (IND != 1) {
#pragma unroll
            for (int p = 0; p < NP; p++) wih2[p] = (v2f){0.f, 0.f};
        }
#pragma unroll
        for (int j = 0; j < HH; j++) whh[j] = 0.f;
    }

    // branchless activation: act = a * sigmoid(m*x) + o  (tanh = 2*sig(2x)-1)
    const float L2E = 1.4426950408889634f;
    const float NEG2L2E = -2.f * L2E;
    float escale = (q == 2) ? NEG2L2E : -L2E;
    float ascale = (q == 2) ? 2.f : 1.f;
    float aoff   = (q == 2) ? -1.f : 0.f;

    float hs[HH];
#pragma unroll
    for (int j = 0; j < HH; j++) hs[j] = 0.f;
    float c = 0.f;

    const int dstep = d ? -IND : IND;             // x row stride (floats)
    const int ostep = d ? -22 : 22;               // out row stride (floats)
    const float* xrow = xin + (size_t)b * TT * IND + (size_t)(d ? (TT - 1) * IND : 0);
    float* orow = out + (size_t)b * TT * 22 + (size_t)(d ? (TT - 1) * 22 : 0) + d * HH + u;
    const bool doStore = (q == 0) && active;

    // register ping-pong x buffers (named scalars/arrays; no address taken)
    v2f   xA[NP > 0 ? NP : 1], xB[NP > 0 ? NP : 1];
    float xA0 = 0.f, xB0 = 0.f;
    if constexpr (IND == 1) {
        xA0 = *xrow;
    } else {
#pragma unroll
        for (int p = 0; p < NP; p++) xA[p] = ((const v2f*)xrow)[p];
    }

#define LSTM_STEP(XC, XN, S)                                                  \
    do {                                                                      \
        v2f va = {bias, 0.f}, vb = {0.f, 0.f};                                \
        float pre;                                                            \
        if constexpr (IND == 1) {                                             \
            pre = fmaf(XC##0, wih0, bias);                                    \
        } else {                                                              \
            _Pragma("unroll")                                                 \
            for (int p = 0; p < NP; p++) {                                    \
                if (p & 1) vb = __builtin_elementwise_fma(XC[p], wih2[p], vb);\
                else       va = __builtin_elementwise_fma(XC[p], wih2[p], va);\
            }                                                                 \
        }                                                                     \
        /* prefetch x for step S+1 (clamped in-bounds on last step) */        \
        {                                                                     \
            const float* xnp = xrow + (((S) + 1 < TT) ? dstep : 0);           \
            if constexpr (IND == 1) {                                         \
                XN##0 = *xnp;                                                 \
            } else {                                                          \
                _Pragma("unroll")                                             \
                for (int p = 0; p < NP; p++) XN[p] = ((const v2f*)xnp)[p];    \
            }                                                                 \
            xrow = xnp;                                                       \
        }                                                                     \
        float ha = 0.f, hb = 0.f;                                             \
        _Pragma("unroll")                                                     \
        for (int j = 0; j < HH; j++) {                                        \
            if (j & 1) hb = fmaf(hs[j], whh[j], hb);                          \
            else       ha = fmaf(hs[j], whh[j], ha);                          \
        }                                                                     \
        if constexpr (IND == 1) pre = pre + ha + hb;                          \
        else pre = (va.x + va.y) + (vb.x + vb.y) + ha + hb;                   \
        float e   = __builtin_amdgcn_exp2f(escale * pre);                     \
        float act = fmaf(ascale, __builtin_amdgcn_rcpf(1.f + e), aoff);       \
        float iv = dpp_q0(act);                                               \
        float fv = dpp_q1(act);                                               \
        float gv = dpp_q2(act);                                               \
        float ov = dpp_q3(act);                                               \
        c = fmaf(fv, c, iv * gv);                                             \
        float e2 = __builtin_amdgcn_exp2f(NEG2L2E * c);                       \
        float th = fmaf(2.f, __builtin_amdgcn_rcpf(1.f + e2), -1.f);          \
        float h  = ov * th;                                                   \
        if (doStore) *orow = h;                                               \
        orow += ostep;                                                        \
        _Pragma("unroll")                                                     \
        for (int j = 0; j < HH; j++) hs[j] = readlane_f(h, 4 * j);            \
    } while (0)

    for (int s = 0; s < TT; s += 2) {
        LSTM_STEP(xA, xB, s);
        LSTM_STEP(xB, xA, s + 1);
    }
#undef LSTM_STEP
}

extern "C" void kernel_launch(void* const* d_in, const int* in_sizes, int n_in,
                              void* d_out, int out_size, void* d_ws, size_t ws_size,
                              hipStream_t stream) {
    const float* x        = (const float*)d_in[0]; // [2048,1,32,512]
    const float* W_ih0    = (const float*)d_in[1]; // [2,44,1]
    const float* W_ih_rest= (const float*)d_in[2]; // [4,2,44,22]
    const float* W_hh     = (const float*)d_in[3]; // [5,2,44,11]
    const float* b_ih     = (const float*)d_in[4]; // [5,2,44]
    const float* b_hh     = (const float*)d_in[5]; // [5,2,44]
    float* out = (float*)d_out;                    // [2048,512,22]

    // Workspace: one ping buffer of chunk*TT*22 floats; largest pow2 chunk
    // that fits ws_size. The x-reduction is staged in the same buffer (its
    // lifetime ends when layer 1 overwrites it). d_out is the pong buffer.
    const size_t perB = (size_t)TT * 22 * sizeof(float);
    int chunk = BB;
    while (chunk > 2 && (size_t)chunk * perB > ws_size) chunk >>= 1;
    float* wsbuf = (float*)d_ws;

    for (int c0 = 0; c0 < BB; c0 += chunk) {
        const float* xc   = x + (size_t)c0 * 32 * TT;
        float*       outc = out + (size_t)c0 * TT * 22;
        const int nblk = (chunk * 2) / 4;  // 4 sequences (waves) per block

        reduce_x<<<dim3(2, chunk), 256, 0, stream>>>(xc, wsbuf);

        lstm_layer<1><<<nblk, 256, 0, stream>>>(wsbuf, outc, W_ih0, W_hh, b_ih, b_hh);

        for (int l = 1; l < NL; l++) {
            const float* src = (l & 1) ? outc : wsbuf;
            float*       dst = (l & 1) ? wsbuf : outc;
            lstm_layer<22><<<nblk, 256, 0, stream>>>(
                src, dst,
                W_ih_rest + (size_t)(l - 1) * 2 * GG * 22,
                W_hh + (size_t)l * 2 * GG * HH,
                b_ih + (size_t)l * 2 * GG,
                b_hh + (size_t)l * 2 * GG);
        }
    }
}